// Round 5
// baseline (434.853 us; speedup 1.0000x reference)
//
#include <hip/hip_runtime.h>
#include <stdint.h>

typedef int v4i  __attribute__((ext_vector_type(4)));
typedef int v16i __attribute__((ext_vector_type(16)));

#define M_TOK 8192
#define N_OUT 4096
#define K_IN  4096

// -------------------------------------------------------------------------
// Pack both carriers into MFMA-fragment-major int8 layouts:
//   T'[g32][c][lane] (16B units): lane holds T[g32*32+(lane&31)]
//   [c*32+(lane>>5)*16 .. +15] — exactly the mfma_i32_32x32x32_i8 operand
//   fragment, so GEMM fragment loads are single coalesced 1KB dwordx4.
// Verified correct for B in R4 (absmax 0).
// -------------------------------------------------------------------------
__device__ __forceinline__ int pack4(int4 a) {
    return (a.x & 255) | ((a.y & 255) << 8) | ((a.z & 255) << 16) | ((a.w & 255) << 24);
}

__device__ __forceinline__ void pack_frag(
    const int* __restrict__ src, int4* __restrict__ dst, int t)
{
    int lane = t & 63;
    int c    = (t >> 6) & 127;              // K granule-pair (32 int8)
    int g32  = t >> 13;                     // 32-row chunk
    int row  = g32 * 32 + (lane & 31);
    int col  = c * 32 + (lane >> 5) * 16;
    const int4* s = (const int4*)(src + (size_t)row * K_IN + col);
    int4 p;
    p.x = pack4(s[0]);
    p.y = pack4(s[1]);
    p.z = pack4(s[2]);
    p.w = pack4(s[3]);
    dst[t] = p;                              // coalesced 16B store
}

__global__ __launch_bounds__(256) void pack_kernel(
    const int* __restrict__ x, const int* __restrict__ w,
    int4* __restrict__ dAp, int4* __restrict__ dBp, int nA16, int nB16)
{
    int i = blockIdx.x * blockDim.x + threadIdx.x;
    if (i < nA16)             pack_frag(x, dAp, i);
    else if (i - nA16 < nB16) pack_frag(w, dBp, i - nA16);
}

// -------------------------------------------------------------------------
// i8 GEMM, ZERO LDS / ZERO BARRIERS: C[M,N] = A[M,K].B[N,K]^T.
// 128x128 block, 4 waves (2x2), wave = 64x64 via 2x2 mfma_i32_32x32x32_i8.
// Both operands pre-swizzled fragment-major; K-loop = 16 coalesced 1KB
// global loads + 16 MFMA per wave, register double-buffered one 128-K iter
// ahead. No __syncthreads -> no vmcnt(0) drain; compiler free to emit
// fine-grained vmcnt (the AITER pattern).
// History: R3 LDS both = 159.5us (LDS pipe ~85% busy); R4 LDS-A+direct-B
// = 169us (per-iter barrier drained prefetches).
// -------------------------------------------------------------------------
__global__ __launch_bounds__(256) void gemm_i8_kernel(
    const int* __restrict__ Ap,        // A' fragment-major
    const int* __restrict__ Bp,        // B' fragment-major
    const float* __restrict__ scale_ptr,
    float* __restrict__ out)           // [M][N] float + 1 scalar
{
    const int tid  = threadIdx.x;
    const int wave = tid >> 6;
    const int lane = tid & 63;

    const int bm = blockIdx.x * 128;   // x-major: consecutive blocks share bn
    const int bn = blockIdx.y * 128;

    const int wm = (wave >> 1) * 64;
    const int wn = (wave & 1) * 64;

    v16i acc[2][2];
#pragma unroll
    for (int i = 0; i < 2; ++i)
#pragma unroll
        for (int j = 0; j < 2; ++j)
#pragma unroll
            for (int r = 0; r < 16; ++r)
                acc[i][j][r] = 0;

    // fragment-major bases: v4i index = (g32*128 + c)*64 + lane
    const v4i* Ab = (const v4i*)Ap + (size_t)((bm + wm) >> 5) * (128 * 64) + lane;
    const v4i* Bb = (const v4i*)Bp + (size_t)((bn + wn) >> 5) * (128 * 64) + lane;

    v4i a0[8], b0[8], a1[8], b1[8];

    // ---- prologue: prefetch k0 = 0 into buf0
#pragma unroll
    for (int t = 0; t < 2; ++t)
#pragma unroll
        for (int kk = 0; kk < 4; ++kk) {
            a0[t * 4 + kk] = Ab[(size_t)(t * 128 + kk) * 64];
            b0[t * 4 + kk] = Bb[(size_t)(t * 128 + kk) * 64];
        }

#pragma unroll 1
    for (int k0 = 0; k0 < K_IN; k0 += 256) {
        // ---- prefetch k0+128 into buf1, compute buf0
        {
            const int cn = (((k0 + 128) & (K_IN - 1)) >> 5);
#pragma unroll
            for (int t = 0; t < 2; ++t)
#pragma unroll
                for (int kk = 0; kk < 4; ++kk) {
                    a1[t * 4 + kk] = Ab[(size_t)(t * 128 + cn + kk) * 64];
                    b1[t * 4 + kk] = Bb[(size_t)(t * 128 + cn + kk) * 64];
                }
#pragma unroll
            for (int kk = 0; kk < 4; ++kk) {
                acc[0][0] = __builtin_amdgcn_mfma_i32_32x32x32_i8(a0[kk],     b0[kk],     acc[0][0], 0, 0, 0);
                acc[0][1] = __builtin_amdgcn_mfma_i32_32x32x32_i8(a0[kk],     b0[4 + kk], acc[0][1], 0, 0, 0);
                acc[1][0] = __builtin_amdgcn_mfma_i32_32x32x32_i8(a0[4 + kk], b0[kk],     acc[1][0], 0, 0, 0);
                acc[1][1] = __builtin_amdgcn_mfma_i32_32x32x32_i8(a0[4 + kk], b0[4 + kk], acc[1][1], 0, 0, 0);
            }
        }
        // ---- prefetch k0+256 into buf0, compute buf1
        {
            const int cn = (((k0 + 256) & (K_IN - 1)) >> 5);
#pragma unroll
            for (int t = 0; t < 2; ++t)
#pragma unroll
                for (int kk = 0; kk < 4; ++kk) {
                    a0[t * 4 + kk] = Ab[(size_t)(t * 128 + cn + kk) * 64];
                    b0[t * 4 + kk] = Bb[(size_t)(t * 128 + cn + kk) * 64];
                }
#pragma unroll
            for (int kk = 0; kk < 4; ++kk) {
                acc[0][0] = __builtin_amdgcn_mfma_i32_32x32x32_i8(a1[kk],     b1[kk],     acc[0][0], 0, 0, 0);
                acc[0][1] = __builtin_amdgcn_mfma_i32_32x32x32_i8(a1[kk],     b1[4 + kk], acc[0][1], 0, 0, 0);
                acc[1][0] = __builtin_amdgcn_mfma_i32_32x32x32_i8(a1[4 + kk], b1[kk],     acc[1][0], 0, 0, 0);
                acc[1][1] = __builtin_amdgcn_mfma_i32_32x32x32_i8(a1[4 + kk], b1[4 + kk], acc[1][1], 0, 0, 0);
            }
        }
    }

    // ---- epilogue: y = clip(rint(acc * scale), -128, 127) as float
    // 32x32 C/D: col = lane&31, row = (r&3) + 8*(r>>2) + 4*(lane>>5)
    const float s     = scale_ptr[0];
    const float scale = (s * 0.1f) / 0.1f;
    const int fm = lane & 31;
    const int fh = lane >> 5;

#pragma unroll
    for (int ti = 0; ti < 2; ++ti) {
#pragma unroll
        for (int tj = 0; tj < 2; ++tj) {
#pragma unroll
            for (int r = 0; r < 16; ++r) {
                int row = bm + wm + ti * 32 + (r & 3) + 8 * (r >> 2) + 4 * fh;
                int col = bn + wn + tj * 32 + fm;
                float y = (float)acc[ti][tj][r] * scale;
                y = rintf(y);
                y = fminf(fmaxf(y, -128.0f), 127.0f);
                out[(size_t)row * N_OUT + col] = y;
            }
        }
    }

    if (bm == 0 && bn == 0 && tid == 0)
        out[(size_t)M_TOK * N_OUT] = 0.1f;
}

// -------------------------------------------------------------------------
extern "C" void kernel_launch(void* const* d_in, const int* in_sizes, int n_in,
                              void* d_out, int out_size, void* d_ws, size_t ws_size,
                              hipStream_t stream)
{
    const int*   x_q     = (const int*)d_in[0];
    const int*   w_q     = (const int*)d_in[1];
    const float* scale_x = (const float*)d_in[2];
    float* out = (float*)d_out;

    char* Ap = (char*)d_ws;                              // 32 MB A'
    char* Bp = (char*)d_ws + (size_t)M_TOK * K_IN;       // 16 MB B'

    const int nA16 = (M_TOK * K_IN) / 16;   // 2097152
    const int nB16 = (N_OUT * K_IN) / 16;   // 1048576

    pack_kernel<<<(nA16 + nB16) / 256, 256, 0, stream>>>(
        x_q, w_q, (int4*)Ap, (int4*)Bp, nA16, nB16);

    // x-major grid: 64 consecutive blocks share bn -> B' panel L2-resident
    dim3 grid(M_TOK / 128, N_OUT / 128);   // (64, 32)
    gemm_i8_kernel<<<grid, 256, 0, stream>>>(
        (const int*)Ap, (const int*)Bp, scale_x, out);
}

// Round 6
// 416.300 us; speedup vs baseline: 1.0446x; 1.0446x over previous
//
#include <hip/hip_runtime.h>
#include <stdint.h>

typedef int v4i  __attribute__((ext_vector_type(4)));
typedef int v16i __attribute__((ext_vector_type(16)));

#define M_TOK 8192
#define N_OUT 4096
#define K_IN  4096

// -------------------------------------------------------------------------
// Pack both int32-carrier tensors into row-major int8 (one dispatch).
// Coalesced: lane reads one int4 (16B), writes one packed int (4B).
// -------------------------------------------------------------------------
__device__ __forceinline__ int pack4(int4 a) {
    return (a.x & 255) | ((a.y & 255) << 8) | ((a.z & 255) << 16) | ((a.w & 255) << 24);
}

__global__ __launch_bounds__(256) void pack_both(
    const int4* __restrict__ x, const int4* __restrict__ w,
    int* __restrict__ dA, int* __restrict__ dB, int n4x, int n4w)
{
    int i = blockIdx.x * blockDim.x + threadIdx.x;
    if (i < n4x) {
        dA[i] = pack4(x[i]);
    } else {
        int j = i - n4x;
        if (j < n4w) dB[j] = pack4(w[j]);
    }
}

// -------------------------------------------------------------------------
// i8 GEMM: C[M,N] = A[M,K].B[N,K]^T. 128x128 tile, BK=128, 4 waves (2x2),
// wave = 64x64 via 2x2 mfma_i32_32x32x32_i8.
// R6 change vs R3: DOUBLE-BUFFERED LDS (2x32KB), staging for iter k+1
// issued BEFORE computing iter k, ONE barrier per iter. The vmcnt(0)
// drain at the barrier lands ~1171 MFMA-cycles after issue -> staging
// latency hidden; barrier count halved (64 -> 32).
// History: R3 single-buf 2-barrier = 159.5us MfmaUtil 40%;
//          R4 barrier+direct-B = 169us; R5 no-LDS = 194us (L2-feed-bound).
// -------------------------------------------------------------------------
__global__ __launch_bounds__(256) void gemm_i8_kernel(
    const char* __restrict__ A8,      // [M][K] int8 row-major
    const char* __restrict__ B8,      // [N][K] int8 row-major
    const float* __restrict__ scale_ptr,
    float* __restrict__ out)          // [M][N] float + 1 scalar at end
{
    __shared__ alignas(16) char lA[2][128 * 128];   // 2 x 16 KB
    __shared__ alignas(16) char lB[2][128 * 128];   // 2 x 16 KB

    const int tid  = threadIdx.x;
    const int wave = tid >> 6;
    const int lane = tid & 63;

    const int bm = blockIdx.y * 128;
    const int bn = blockIdx.x * 128;   // x-major over N: consecutive blocks share A-panel (R3 mapping)

    const int wm = (wave >> 1) * 64;
    const int wn = (wave & 1) * 64;

    v16i acc[2][2];
#pragma unroll
    for (int i = 0; i < 2; ++i)
#pragma unroll
        for (int j = 0; j < 2; ++j)
#pragma unroll
            for (int r = 0; r < 16; ++r)
                acc[i][j][r] = 0;

    // ---- staging geometry (verified R3): wave stages rows [32w,32w+32) of
    // each operand tile, 4 chunks of 8 rows x 128B; global column granule
    // XOR-swizzled by row&7 so fragment reads are conflict-free.
    const int srow = lane >> 3;
    const int scol = ((lane & 7) ^ srow) << 4;

    const char* gA[4]; const char* gB[4];
    char* lAp[2][4]; char* lBp[2][4];
#pragma unroll
    for (int q = 0; q < 4; ++q) {
        int row0 = wave * 32 + q * 8;
        gA[q] = A8 + (size_t)(bm + row0 + srow) * K_IN + scol;
        gB[q] = B8 + (size_t)(bn + row0 + srow) * K_IN + scol;
        lAp[0][q] = lA[0] + row0 * 128;
        lAp[1][q] = lA[1] + row0 * 128;
        lBp[0][q] = lB[0] + row0 * 128;
        lBp[1][q] = lB[1] + row0 * 128;
    }

    // ---- fragment geometry (verified R3):
    // A[m=lane&31][k=(lane>>5)*16+j]; read-side unswizzle by m&7.
    const int fm  = lane & 31;
    const int fh  = lane >> 5;
    const int fsw = fm & 7;

#define STAGE(koff, buf)                                                      \
    {                                                                         \
        _Pragma("unroll")                                                     \
        for (int q = 0; q < 4; ++q) {                                         \
            __builtin_amdgcn_global_load_lds(                                 \
                (const __attribute__((address_space(1))) void*)(gA[q] + (koff)), \
                (__attribute__((address_space(3))) void*)lAp[buf][q], 16, 0, 0); \
            __builtin_amdgcn_global_load_lds(                                 \
                (const __attribute__((address_space(1))) void*)(gB[q] + (koff)), \
                (__attribute__((address_space(3))) void*)lBp[buf][q], 16, 0, 0); \
        }                                                                     \
    }

#define COMPUTE(buf)                                                          \
    {                                                                         \
        _Pragma("unroll")                                                     \
        for (int kk = 0; kk < 4; ++kk) {                                      \
            const int goff = ((kk * 2 + fh) ^ fsw) << 4;                      \
            v4i af0 = *(const v4i*)(lA[buf] + (wm + fm) * 128 + goff);        \
            v4i af1 = *(const v4i*)(lA[buf] + (wm + 32 + fm) * 128 + goff);   \
            v4i bf0 = *(const v4i*)(lB[buf] + (wn + fm) * 128 + goff);        \
            v4i bf1 = *(const v4i*)(lB[buf] + (wn + 32 + fm) * 128 + goff);   \
            acc[0][0] = __builtin_amdgcn_mfma_i32_32x32x32_i8(af0, bf0, acc[0][0], 0, 0, 0); \
            acc[0][1] = __builtin_amdgcn_mfma_i32_32x32x32_i8(af0, bf1, acc[0][1], 0, 0, 0); \
            acc[1][0] = __builtin_amdgcn_mfma_i32_32x32x32_i8(af1, bf0, acc[1][0], 0, 0, 0); \
            acc[1][1] = __builtin_amdgcn_mfma_i32_32x32x32_i8(af1, bf1, acc[1][1], 0, 0, 0); \
        }                                                                     \
    }

    // ---- prologue: stage tile 0 into buf0
    STAGE(0, 0);
    __syncthreads();

#pragma unroll 1
    for (int k0 = 0; k0 < K_IN; k0 += 256) {
        // even half: prefetch k0+128 -> buf1, compute buf0
        if (k0 + 128 < K_IN) STAGE(k0 + 128, 1);
        COMPUTE(0);
        __syncthreads();   // drain lands ~1 compute-phase after issue
        // odd half: prefetch k0+256 -> buf0, compute buf1
        if (k0 + 256 < K_IN) STAGE(k0 + 256, 0);
        COMPUTE(1);
        __syncthreads();
    }

#undef STAGE
#undef COMPUTE

    // ---- epilogue (verified R3): y = clip(rint(acc*scale), -128, 127)
    // 32x32 C/D: col = lane&31, row = (r&3) + 8*(r>>2) + 4*(lane>>5)
    const float s     = scale_ptr[0];
    const float scale = (s * 0.1f) / 0.1f;

#pragma unroll
    for (int ti = 0; ti < 2; ++ti) {
#pragma unroll
        for (int tj = 0; tj < 2; ++tj) {
#pragma unroll
            for (int r = 0; r < 16; ++r) {
                int row = bm + wm + ti * 32 + (r & 3) + 8 * (r >> 2) + 4 * fh;
                int col = bn + wn + tj * 32 + fm;
                float y = (float)acc[ti][tj][r] * scale;
                y = rintf(y);
                y = fminf(fmaxf(y, -128.0f), 127.0f);
                out[(size_t)row * N_OUT + col] = y;
            }
        }
    }

    if (bm == 0 && bn == 0 && tid == 0)
        out[(size_t)M_TOK * N_OUT] = 0.1f;
}

// -------------------------------------------------------------------------
extern "C" void kernel_launch(void* const* d_in, const int* in_sizes, int n_in,
                              void* d_out, int out_size, void* d_ws, size_t ws_size,
                              hipStream_t stream)
{
    const int*   x_q     = (const int*)d_in[0];
    const int*   w_q     = (const int*)d_in[1];
    const float* scale_x = (const float*)d_in[2];
    float* out = (float*)d_out;

    char* A8 = (char*)d_ws;                              // 32 MB
    char* B8 = (char*)d_ws + (size_t)M_TOK * K_IN;       // 16 MB

    const int n4x = (M_TOK * K_IN) / 4;
    const int n4w = (N_OUT * K_IN) / 4;

    pack_both<<<(n4x + n4w) / 256, 256, 0, stream>>>(
        (const int4*)x_q, (const int4*)w_q, (int*)A8, (int*)B8, n4x, n4w);

    dim3 grid(N_OUT / 128, M_TOK / 128);   // R3 mapping (x over N)
    gemm_i8_kernel<<<grid, 256, 0, stream>>>(A8, B8, scale_x, out);
}

// Round 7
// 405.454 us; speedup vs baseline: 1.0725x; 1.0267x over previous
//
#include <hip/hip_runtime.h>
#include <stdint.h>

typedef int v4i  __attribute__((ext_vector_type(4)));
typedef int v16i __attribute__((ext_vector_type(16)));

#define M_TOK 8192
#define N_OUT 4096
#define K_IN  4096

// -------------------------------------------------------------------------
// Pack: x -> A8 row-major int8 (coalesced 16B-read/4B-write).
//       w -> B' MFMA-fragment-major int8 (verified R4/R5):
//   B'[n32][c][lane] (16B units): lane holds B[n32*32+(lane&31)]
//   [c*32+(lane>>5)*16 .. +15] — one coalesced 1KB dwordx4 per fragment.
// -------------------------------------------------------------------------
__device__ __forceinline__ int pack4(int4 a) {
    return (a.x & 255) | ((a.y & 255) << 8) | ((a.z & 255) << 16) | ((a.w & 255) << 24);
}

__global__ __launch_bounds__(256) void pack_kernel(
    const int4* __restrict__ x, const int* __restrict__ w,
    int* __restrict__ dA, int4* __restrict__ dBp, int n4x, int nB16)
{
    int i = blockIdx.x * blockDim.x + threadIdx.x;
    if (i < n4x) {
        dA[i] = pack4(x[i]);
    } else {
        int t = i - n4x;
        if (t < nB16) {
            int lane = t & 63;
            int c    = (t >> 6) & 127;
            int n32  = t >> 13;
            int row  = n32 * 32 + (lane & 31);
            int col  = c * 32 + (lane >> 5) * 16;
            const int4* s = (const int4*)(w + (size_t)row * K_IN + col);
            int4 p;
            p.x = pack4(s[0]);
            p.y = pack4(s[1]);
            p.z = pack4(s[2]);
            p.w = pack4(s[3]);
            dBp[t] = p;
        }
    }
}

// -------------------------------------------------------------------------
// i8 GEMM, split-feed: C[M,N] = A[M,K].B[N,K]^T.
// Block 128x256, 4 waves (2M x 2N), wave tile 64x128 = 2x4 of
// mfma_i32_32x32x32_i8 (acc 128 VGPR).
//  - A: LDS double-buffered 2x16KB, global_load_lds w=16, XOR-swizzled.
//    Stage(k+1) issued BEFORE compute -> end-of-iter vmcnt(0) drain hidden.
//  - B: direct global->reg from fragment-major B', all 16 frags issued
//    post-barrier in kk-major order -> fine-grained never-zero vmcnt.
//  - ONE barrier per 128-K iter.
// Model: LDS 640 cyc + vector 70 B/cyc vs MFMA 1171 cyc per block-iter.
// History: R3 all-LDS 64x64 = 159.5us (LDS 1.3-2.2x over); R4 169; R5 194;
//          R6 dbuf-all-LDS 181.
// -------------------------------------------------------------------------
__global__ __launch_bounds__(256, 2) void gemm_i8_kernel(
    const char* __restrict__ A8,       // [M][K] int8 row-major
    const int*  __restrict__ Bp,       // B' fragment-major
    const float* __restrict__ scale_ptr,
    float* __restrict__ out)           // [M][N] float + 1 scalar
{
    __shared__ alignas(16) char lA[2][128 * 128];   // 2 x 16 KB

    const int tid  = threadIdx.x;
    const int wave = tid >> 6;
    const int lane = tid & 63;

    const int bm = blockIdx.x * 128;   // x over M: 64 blocks share B' panel
    const int bn = blockIdx.y * 256;

    const int wm = (wave >> 1) * 64;
    const int wn = (wave & 1) * 128;

    v16i acc[2][4];
#pragma unroll
    for (int i = 0; i < 2; ++i)
#pragma unroll
        for (int j = 0; j < 4; ++j)
#pragma unroll
            for (int r = 0; r < 16; ++r)
                acc[i][j][r] = 0;

    // ---- A staging geometry (R3-verified): wave stages rows [32w,32w+32)
    // of the 128-row A tile, 4 chunks of 8 rows x 128B; source column
    // granule XOR-swizzled by row&7 -> conflict-free fragment reads.
    const int srow = lane >> 3;
    const int scol = ((lane & 7) ^ srow) << 4;

    const char* gA[4];
    char* lAp[2][4];
#pragma unroll
    for (int q = 0; q < 4; ++q) {
        int row0 = wave * 32 + q * 8;
        gA[q]     = A8 + (size_t)(bm + row0 + srow) * K_IN + scol;
        lAp[0][q] = lA[0] + row0 * 128;
        lAp[1][q] = lA[1] + row0 * 128;
    }

    // ---- B' base: v4i index = (n32*128 + c)*64 + lane
    const v4i* Bb = (const v4i*)Bp + (size_t)((bn + wn) >> 5) * (128 * 64) + lane;

    // ---- fragment geometry (R3-verified): A[m=lane&31][k=(lane>>5)*16+j]
    const int fm  = lane & 31;
    const int fh  = lane >> 5;
    const int fsw = fm & 7;

#define STAGE_A(koff, buf)                                                    \
    {                                                                         \
        _Pragma("unroll")                                                     \
        for (int q = 0; q < 4; ++q)                                           \
            __builtin_amdgcn_global_load_lds(                                 \
                (const __attribute__((address_space(1))) void*)(gA[q] + (koff)), \
                (__attribute__((address_space(3))) void*)lAp[buf][q], 16, 0, 0); \
    }

    // ---- prologue: stage A(0) into buf0
    STAGE_A(0, 0);
    __syncthreads();

#pragma unroll 1
    for (int k0 = 0; k0 < K_IN; k0 += 128) {
        const int cur = (k0 >> 7) & 1;
        const int c0  = k0 >> 5;       // K granule base for this iter

        // B fragments for this iter: kk-major issue order so the first
        // MFMAs release at vmcnt(12) while later loads are still in flight.
        v4i bf[4][4];
#pragma unroll
        for (int kk = 0; kk < 4; ++kk)
#pragma unroll
            for (int t = 0; t < 4; ++t)
                bf[kk][t] = Bb[(size_t)(t * 128 + c0 + kk) * 64];

        // stage A(k+1) into the other buffer BEFORE compute -> the barrier
        // drain at iter end lands ~1171 MFMA-cycles after issue.
        if (k0 + 128 < K_IN) STAGE_A(k0 + 128, cur ^ 1);

#pragma unroll
        for (int kk = 0; kk < 4; ++kk) {
            const int goff = ((kk * 2 + fh) ^ fsw) << 4;
            v4i af0 = *(const v4i*)(lA[cur] + (wm + fm) * 128 + goff);
            v4i af1 = *(const v4i*)(lA[cur] + (wm + 32 + fm) * 128 + goff);
#pragma unroll
            for (int t = 0; t < 4; ++t) {
                acc[0][t] = __builtin_amdgcn_mfma_i32_32x32x32_i8(af0, bf[kk][t], acc[0][t], 0, 0, 0);
                acc[1][t] = __builtin_amdgcn_mfma_i32_32x32x32_i8(af1, bf[kk][t], acc[1][t], 0, 0, 0);
            }
        }

        __syncthreads();   // single barrier per iter; staged A drain hidden
    }

#undef STAGE_A

    // ---- epilogue (verified): y = clip(rint(acc*scale), -128, 127)
    // 32x32 C/D: col = lane&31, row = (r&3) + 8*(r>>2) + 4*(lane>>5)
    const float s     = scale_ptr[0];
    const float scale = (s * 0.1f) / 0.1f;

#pragma unroll
    for (int ti = 0; ti < 2; ++ti) {
#pragma unroll
        for (int tj = 0; tj < 4; ++tj) {
#pragma unroll
            for (int r = 0; r < 16; ++r) {
                int row = bm + wm + ti * 32 + (r & 3) + 8 * (r >> 2) + 4 * fh;
                int col = bn + wn + tj * 32 + fm;
                float y = (float)acc[ti][tj][r] * scale;
                y = rintf(y);
                y = fminf(fmaxf(y, -128.0f), 127.0f);
                out[(size_t)row * N_OUT + col] = y;
            }
        }
    }

    if (bm == 0 && bn == 0 && tid == 0)
        out[(size_t)M_TOK * N_OUT] = 0.1f;
}

// -------------------------------------------------------------------------
extern "C" void kernel_launch(void* const* d_in, const int* in_sizes, int n_in,
                              void* d_out, int out_size, void* d_ws, size_t ws_size,
                              hipStream_t stream)
{
    const int*   x_q     = (const int*)d_in[0];
    const int*   w_q     = (const int*)d_in[1];
    const float* scale_x = (const float*)d_in[2];
    float* out = (float*)d_out;

    char* A8 = (char*)d_ws;                              // 32 MB row-major A
    char* Bp = (char*)d_ws + (size_t)M_TOK * K_IN;       // 16 MB B' frag-major

    const int n4x  = (M_TOK * K_IN) / 4;    // 8388608
    const int nB16 = (N_OUT * K_IN) / 16;   // 1048576

    pack_kernel<<<(n4x + nB16 + 255) / 256, 256, 0, stream>>>(
        (const int4*)x_q, w_q, (int*)A8, (int4*)Bp, n4x, nB16);

    // x over M: 64 consecutive blocks share one 1MB B' panel (L2-resident)
    dim3 grid(M_TOK / 128, N_OUT / 256);   // (64, 16) = 1024 blocks
    gemm_i8_kernel<<<grid, 256, 0, stream>>>(
        A8, (const int*)Bp, scale_x, out);
}